// Round 1
// baseline (580.159 us; speedup 1.0000x reference)
//
#include <hip/hip_runtime.h>
#include <math.h>
#include <stdint.h>

namespace {

constexpr int T = 50;
constexpr int NB = 32768;
constexpr int H = 128;
constexpr int NTHREADS = 512;   // 8 waves = 2 waves/SIMD (1 block/CU)
constexpr int BLK_ROWS = 128;   // 4 wave-pairs x 32 rows

typedef float v4f __attribute__((ext_vector_type(4)));
typedef float v2f __attribute__((ext_vector_type(2)));
typedef unsigned int v4u __attribute__((ext_vector_type(4)));
typedef short short8 __attribute__((ext_vector_type(8)));

union FU { float f; uint32_t u; };
union U8 { uint32_t u[4]; short8 v; };

__device__ __forceinline__ uint32_t pack_hi16(uint32_t odd, uint32_t even) {
  return (odd & 0xFFFF0000u) | (even >> 16);
}
__device__ __forceinline__ uint32_t pack_lo16(uint32_t odd, uint32_t even) {
  return (odd << 16) | (even & 0xFFFFu);
}

// 2-way bf16 split (truncation): a ~= bf16(hi)+bf16(mid), residual <= 2^-16 |a|
__device__ __forceinline__ void split2(float a, uint32_t& hi, uint32_t& mid) {
  FU c0; c0.f = a;
  uint32_t uh = c0.u & 0xFFFF0000u;
  FU fh; fh.u = uh;
  float r1 = a - fh.f;   // exact
  FU c1; c1.f = r1;
  hi = uh; mid = c1.u & 0xFFFF0000u;
}
// 3-way exact bf16 split
__device__ __forceinline__ void split3(float a, uint32_t& hi, uint32_t& mid, uint32_t& lo) {
  FU c0; c0.f = a;
  uint32_t uh = c0.u & 0xFFFF0000u;
  FU fh; fh.u = uh;
  float r1 = a - fh.f;
  FU c1; c1.f = r1;
  uint32_t um = c1.u & 0xFFFF0000u;
  FU fm; fm.u = um;
  float r2 = r1 - fm.f;
  FU c2; c2.f = r2;
  hi = uh; mid = um; lo = c2.u;
}

__device__ __forceinline__ v4f mfma16(short8 a, short8 b, v4f c) {
  return __builtin_amdgcn_mfma_f32_16x16x32_bf16(a, b, c, 0, 0, 0);
}

__global__ __launch_bounds__(NTHREADS, 2)
void fwdsim5(const float* __restrict__ proj,   // (B, 64)
             const float* __restrict__ idm,    // (B, T, 12)
             const float* __restrict__ merg,   // (B, T, 3)
             const float* __restrict__ W1,     // (73, 128)
             const float* __restrict__ b1,     // (128)
             const float* __restrict__ W2,     // (128, 128)
             const float* __restrict__ b2,     // (128)
             const float* __restrict__ W3,     // (128, 1)
             const float* __restrict__ b3,     // (1)
             const float* __restrict__ smean,  // (6)
             const float* __restrict__ svar,   // (6)
             float* __restrict__ out)          // (B, T)
{
  // h exchange buffer: [pair][row 32][col pad 132] packed bf16 hi|mid.
  // Prologue reuses this space as the W1[0:64] 3-plane frag store (48 KiB).
  __shared__ __align__(16) uint32_t sH[4 * 32 * 132];   // 67584 B
  // base1 (b1 + proj@W1[0:64]) fp32, shared per pair: [pair][col 128][row pad 36]
  __shared__ __align__(16) float sBase[4 * 128 * 36];   // 73728 B
  // W1 env rows 64..72 (zero-padded to K=32), 2-plane frags: [nt][plane][lane]
  __shared__ short8 sEnvB[8 * 2 * 64];                  // 16384 B
  // layer-3 partials: [buf][pair][member][row 32]
  __shared__ __align__(16) float sAct[2][4][2][32];     // 2048 B
  // total 159744 B <= 160 KiB

  const int tid  = threadIdx.x;
  const int wave = tid >> 6;
  const int lane = tid & 63;
  const int pair = wave >> 1;   // 0..3
  const int pm   = wave & 1;    // member 0/1: owns output cols pm*64..pm*64+63
  const int gq   = lane >> 4;   // 0..3
  const int o    = lane & 15;   // 0..15
  const int pair_row0 = blockIdx.x * BLK_ROWS + pair * 32;

  short8* sW1b = (short8*)sH;   // prologue-only alias (49152 B < 67584 B)

  // ---- stage W1[0:64] 3-plane frags into sW1b ----
  for (int job = tid; job < 1024; job += NTHREADS) {
    const int lj = job & 63, ktnt = job >> 6;
    const int k0 = (ktnt >> 3) * 32 + (lj >> 4) * 8;
    const int n  = (ktnt & 7) * 16 + (lj & 15);
    uint32_t hi[8], mi[8], lo[8];
#pragma unroll
    for (int j = 0; j < 8; ++j) split3(W1[(k0 + j) * H + n], hi[j], mi[j], lo[j]);
    U8 fh, fm, fl;
#pragma unroll
    for (int d = 0; d < 4; ++d) {
      fh.u[d] = pack_hi16(hi[2*d+1], hi[2*d]);
      fm.u[d] = pack_hi16(mi[2*d+1], mi[2*d]);
      fl.u[d] = pack_hi16(lo[2*d+1], lo[2*d]);
    }
    sW1b[(ktnt * 3 + 0) * 64 + lj] = fh.v;
    sW1b[(ktnt * 3 + 1) * 64 + lj] = fm.v;
    sW1b[(ktnt * 3 + 2) * 64 + lj] = fl.v;
  }
  // ---- stage W1env 2-plane frags (k = 0..8 live, rest zero) ----
  for (int job = tid; job < 512; job += NTHREADS) {
    const int lj = job & 63, nt = job >> 6;
    const int k0 = (lj >> 4) * 8;
    const int n  = nt * 16 + (lj & 15);
    uint32_t hi[8], mi[8];
#pragma unroll
    for (int j = 0; j < 8; ++j) {
      const int k = k0 + j;
      const float w = (k < 9) ? W1[(64 + k) * H + n] : 0.f;
      split2(w, hi[j], mi[j]);
    }
    U8 fh, fm;
#pragma unroll
    for (int d = 0; d < 4; ++d) {
      fh.u[d] = pack_hi16(hi[2*d+1], hi[2*d]);
      fm.u[d] = pack_hi16(mi[2*d+1], mi[2*d]);
    }
    sEnvB[(nt * 2 + 0) * 64 + lj] = fh.v;
    sEnvB[(nt * 2 + 1) * 64 + lj] = fm.v;
  }

  // ---- W2 -> persistent register B-frags, ONLY this member's 4 col-tiles ----
  short8 w2h[16], w2m[16];   // [kt*4+ntl], 2 planes = 128 regs
#pragma unroll
  for (int kt = 0; kt < 4; ++kt)
#pragma unroll
    for (int ntl = 0; ntl < 4; ++ntl) {
      const int k0 = kt * 32 + gq * 8;
      const int n  = (pm * 4 + ntl) * 16 + o;
      uint32_t hi[8], mi[8];
#pragma unroll
      for (int j = 0; j < 8; ++j) split2(W2[(k0 + j) * H + n], hi[j], mi[j]);
      U8 fh, fm;
#pragma unroll
      for (int d = 0; d < 4; ++d) {
        fh.u[d] = pack_hi16(hi[2*d+1], hi[2*d]);
        fm.u[d] = pack_hi16(mi[2*d+1], mi[2*d]);
      }
      w2h[kt*4+ntl] = fh.v;
      w2m[kt*4+ntl] = fm.v;
    }

  // ---- scalars ----
  float mean[6], istd[6];
#pragma unroll
  for (int c = 0; c < 6; ++c) { mean[c] = smean[c]; istd[c] = 1.0f / sqrtf(svar[c]); }
  const float b3v = b3[0];
  float b1c[4], b2c[4], W3c[4];
#pragma unroll
  for (int ntl = 0; ntl < 4; ++ntl) {
    const int n = (pm * 4 + ntl) * 16 + o;
    b1c[ntl] = b1[n]; b2c[ntl] = b2[n]; W3c[ntl] = W3[n];
  }

  __syncthreads();   // frag planes ready

  // ---- base1 = b1 + proj @ W1[0:64], member's 4 col-tiles -> sBase ----
#pragma unroll
  for (int mt = 0; mt < 2; ++mt) {
    const int row = pair_row0 + mt * 16 + o;
    short8 pah[2], pam[2], pal[2];
#pragma unroll
    for (int kt = 0; kt < 2; ++kt) {
      const float* pp = proj + (size_t)row * 64 + kt * 32 + gq * 8;
      v4f p0 = *(const v4f*)pp;
      v4f p1 = *(const v4f*)(pp + 4);
      uint32_t hi[8], mi[8], lo[8];
#pragma unroll
      for (int e = 0; e < 4; ++e) split3(p0[e], hi[e],   mi[e],   lo[e]);
#pragma unroll
      for (int e = 0; e < 4; ++e) split3(p1[e], hi[4+e], mi[4+e], lo[4+e]);
      U8 uh, um, ul;
#pragma unroll
      for (int d = 0; d < 4; ++d) {
        uh.u[d] = pack_hi16(hi[2*d+1], hi[2*d]);
        um.u[d] = pack_hi16(mi[2*d+1], mi[2*d]);
        ul.u[d] = pack_hi16(lo[2*d+1], lo[2*d]);
      }
      pah[kt] = uh.v; pam[kt] = um.v; pal[kt] = ul.v;
    }
    v4f acc[4];
#pragma unroll
    for (int ntl = 0; ntl < 4; ++ntl)
      acc[ntl] = (v4f){b1c[ntl], b1c[ntl], b1c[ntl], b1c[ntl]};
#pragma unroll
    for (int kt = 0; kt < 2; ++kt)
#pragma unroll
      for (int ntl = 0; ntl < 4; ++ntl) {
        const int nt = pm * 4 + ntl;
        short8 bh = sW1b[((kt*8+nt)*3 + 0) * 64 + lane];
        short8 bm = sW1b[((kt*8+nt)*3 + 1) * 64 + lane];
        short8 bl = sW1b[((kt*8+nt)*3 + 2) * 64 + lane];
        acc[ntl] = mfma16(pah[kt], bl, acc[ntl]);
        acc[ntl] = mfma16(pal[kt], bh, acc[ntl]);
        acc[ntl] = mfma16(pam[kt], bm, acc[ntl]);
        acc[ntl] = mfma16(pah[kt], bm, acc[ntl]);
        acc[ntl] = mfma16(pam[kt], bh, acc[ntl]);
        acc[ntl] = mfma16(pah[kt], bh, acc[ntl]);
      }
#pragma unroll
    for (int ntl = 0; ntl < 4; ++ntl) {
      const int nt = pm * 4 + ntl;
      float* dst = &sBase[(pair * 128 + nt*16 + o) * 36 + mt*16 + 4*gq];
      *(v4f*)dst = acc[ntl];   // C layout: rows 4gq+r, col nt*16+o
    }
  }
  __syncthreads();   // base done; sW1b region now reusable as sH

  // ---- recurrent state: lane owns rows o (Mt0), 16+o (Mt1), replicated over gq ----
  float ego_v[2], ego_x[2], act[2] = {0.f, 0.f};
  const float* idmp[2] = { idm + (size_t)(pair_row0 + o) * (T*12),
                           idm + (size_t)(pair_row0 + 16 + o) * (T*12) };
  const float* mrgp[2] = { merg + (size_t)(pair_row0 + o) * (T*3),
                           merg + (size_t)(pair_row0 + 16 + o) * (T*3) };
  v4f sa[2]; v2f fb[2]; float exr[2], m0[2], m1[2], m2[2];
#pragma unroll
  for (int mt = 0; mt < 2; ++mt) {
    sa[mt] = *(const v4f*)idmp[mt];
    fb[mt] = *(const v2f*)(idmp[mt] + 4);
    exr[mt] = idmp[mt][11];
    m0[mt] = mrgp[mt][0]; m1[mt] = mrgp[mt][1]; m2[mt] = mrgp[mt][2];
  }

  int buf = 0;

#pragma unroll 1
  for (int t = 0; t < T; ++t) {
    // ---- state + env ----
    float xk[2][9];
#pragma unroll
    for (int mt = 0; mt < 2; ++mt) {
      const float s0 = sa[mt][0], fv = sa[mt][1], mv = sa[mt][2], s3 = sa[mt][3];
      const float fgx = fb[mt][0], mgx = fb[mt][1];
      const float ex = exr[mt];
      if (t == 0) { ego_v[mt] = s0; ego_x[mt] = s3; }
      else {
        ego_v[mt] += act[mt] * 0.1f;
        ego_x[mt] += ego_v[mt] * 0.1f + act[mt] * 0.005f;
      }
      xk[mt][0] = (ego_v[mt]                                      - mean[0]) * istd[0];
      xk[mt][1] = (fv                                             - mean[1]) * istd[1];
      xk[mt][2] = (ego_v[mt] - fv                                 - mean[2]) * istd[2];
      xk[mt][3] = (fgx - ego_x[mt]                                - mean[3]) * istd[3];
      xk[mt][4] = ((ego_v[mt] - mv) * ex                          - mean[4]) * istd[4];
      xk[mt][5] = ((mgx - ego_x[mt]) * ex + (1.0f - ex) * 100.0f  - mean[5]) * istd[5];
      xk[mt][6] = m0[mt]; xk[mt][7] = m1[mt]; xk[mt][8] = m2[mt];
    }
    // reload next step's inputs in place (hidden under the rest of the step)
    {
      const int tn = (t + 1 < T) ? t + 1 : t;
#pragma unroll
      for (int mt = 0; mt < 2; ++mt) {
        const float* ip = idmp[mt] + tn * 12;
        sa[mt] = *(const v4f*)ip;  fb[mt] = *(const v2f*)(ip + 4);  exr[mt] = ip[11];
        const float* mp = mrgp[mt] + tn * 3;
        m0[mt] = mp[0]; m1[mt] = mp[1]; m2[mt] = mp[2];
      }
    }

    // ---- env A-frags: A[m=o][k=8gq+j]; dims 9..31 zero ----
    short8 eh[2], em[2];
#pragma unroll
    for (int mt = 0; mt < 2; ++mt) {
      uint32_t hi[8], mi[8];
#pragma unroll
      for (int j = 0; j < 8; ++j) {
        float v = (gq == 0) ? xk[mt][j] : ((gq == 1 && j == 0) ? xk[mt][8] : 0.f);
        split2(v, hi[j], mi[j]);
      }
      U8 uh, um;
#pragma unroll
      for (int d = 0; d < 4; ++d) {
        uh.u[d] = pack_hi16(hi[2*d+1], hi[2*d]);
        um.u[d] = pack_hi16(mi[2*d+1], mi[2*d]);
      }
      eh[mt] = uh.v; em[mt] = um.v;
    }

    // ---- layer 1 (member's 4 col-tiles) -> packed h -> sH ----
#pragma unroll
    for (int mt = 0; mt < 2; ++mt)
#pragma unroll
      for (int ntl = 0; ntl < 4; ++ntl) {
        const int nt = pm * 4 + ntl;
        v4f a1 = *(const v4f*)&sBase[(pair * 128 + nt*16 + o) * 36 + mt*16 + 4*gq];
        short8 bh = sEnvB[(nt*2 + 0) * 64 + lane];
        short8 bm = sEnvB[(nt*2 + 1) * 64 + lane];
        a1 = mfma16(eh[mt], bm, a1);
        a1 = mfma16(em[mt], bh, a1);
        a1 = mfma16(eh[mt], bh, a1);
#pragma unroll
        for (int r = 0; r < 4; ++r) {
          const float hv = fmaxf(a1[r], 0.f);
          uint32_t hi, mi; split2(hv, hi, mi);
          sH[(pair*32 + mt*16 + 4*gq + r) * 132 + nt*16 + o] = hi | (mi >> 16);
        }
      }

    __syncthreads();   // B1: full h visible to both pair members

    // ---- layer 2: full-K A-frags from sH, member's 4 col-tiles ----
    v4f acc2[2][4];
#pragma unroll
    for (int mt = 0; mt < 2; ++mt)
#pragma unroll
      for (int ntl = 0; ntl < 4; ++ntl)
        acc2[mt][ntl] = (v4f){b2c[ntl], b2c[ntl], b2c[ntl], b2c[ntl]};

#pragma unroll
    for (int mt = 0; mt < 2; ++mt)
#pragma unroll
      for (int kt = 0; kt < 4; ++kt) {
        const uint32_t* src = &sH[(pair*32 + mt*16 + o) * 132 + kt*32 + gq*8];
        v4u q0 = *(const v4u*)src;
        v4u q1 = *(const v4u*)(src + 4);
        uint32_t u[8] = {q0[0], q0[1], q0[2], q0[3], q1[0], q1[1], q1[2], q1[3]};
        U8 uh, um;
#pragma unroll
        for (int d = 0; d < 4; ++d) {
          uh.u[d] = pack_hi16(u[2*d+1], u[2*d]);   // hi plane (top16 of packed)
          um.u[d] = pack_lo16(u[2*d+1], u[2*d]);   // mid plane (low16 of packed)
        }
        short8 ah = uh.v, am = um.v;
#pragma unroll
        for (int ntl = 0; ntl < 4; ++ntl) {
          acc2[mt][ntl] = mfma16(ah, w2m[kt*4 + ntl], acc2[mt][ntl]);
          acc2[mt][ntl] = mfma16(am, w2h[kt*4 + ntl], acc2[mt][ntl]);
          acc2[mt][ntl] = mfma16(ah, w2h[kt*4 + ntl], acc2[mt][ntl]);
        }
      }

    // ---- layer 3 partial over member's 64 cols ----
    v4f part[2] = {(v4f){0.f,0.f,0.f,0.f}, (v4f){0.f,0.f,0.f,0.f}};
#pragma unroll
    for (int mt = 0; mt < 2; ++mt)
#pragma unroll
      for (int ntl = 0; ntl < 4; ++ntl) {
        v4f h = acc2[mt][ntl];
#pragma unroll
        for (int r = 0; r < 4; ++r) part[mt][r] += fmaxf(h[r], 0.f) * W3c[ntl];
      }
#pragma unroll
    for (int m = 1; m <= 8; m <<= 1)
#pragma unroll
      for (int mt = 0; mt < 2; ++mt)
#pragma unroll
        for (int r = 0; r < 4; ++r) part[mt][r] += __shfl_xor(part[mt][r], m, 64);

    // lanes o==0 (one per gq) publish rows 4gq+r / 16+4gq+r
    if (o == 0) {
      *(v4f*)&sAct[buf][pair][pm][     4*gq] = part[0];
      *(v4f*)&sAct[buf][pair][pm][16 + 4*gq] = part[1];
    }

    __syncthreads();   // B2: partials visible; also protects sH WAR for t+1

    act[0] = sAct[buf][pair][0][o]      + sAct[buf][pair][1][o]      + b3v;
    act[1] = sAct[buf][pair][0][16 + o] + sAct[buf][pair][1][16 + o] + b3v;

    if (pm == 0 && gq == 0) {
      out[(size_t)(pair_row0 + o)      * T + t] = act[0];
      out[(size_t)(pair_row0 + 16 + o) * T + t] = act[1];
    }
    buf ^= 1;
  }
}

}  // namespace

extern "C" void kernel_launch(void* const* d_in, const int* in_sizes, int n_in,
                              void* d_out, int out_size, void* d_ws, size_t ws_size,
                              hipStream_t stream) {
  const float* proj  = (const float*)d_in[0];
  const float* idm   = (const float*)d_in[1];
  const float* merg  = (const float*)d_in[2];
  const float* W1    = (const float*)d_in[3];
  const float* b1    = (const float*)d_in[4];
  const float* W2    = (const float*)d_in[5];
  const float* b2    = (const float*)d_in[6];
  const float* W3    = (const float*)d_in[7];
  const float* b3    = (const float*)d_in[8];
  const float* smean = (const float*)d_in[9];
  const float* svar  = (const float*)d_in[10];
  // d_in[11] = rollout_len (fixed 50)

  dim3 grid(NB / BLK_ROWS);   // 256 blocks -> 1 per CU
  dim3 block(NTHREADS);       // 512 threads = 8 waves (4 pairs x 32 rows)
  hipLaunchKernelGGL(fwdsim5, grid, block, 0, stream,
                     proj, idm, merg, W1, b1, W2, b2, W3, b3, smean, svar,
                     (float*)d_out);
}

// Round 2
// 405.424 us; speedup vs baseline: 1.4310x; 1.4310x over previous
//
#include <hip/hip_runtime.h>
#include <math.h>
#include <stdint.h>

namespace {

constexpr int T = 50;
constexpr int NB = 32768;
constexpr int H = 128;
constexpr int NTHREADS = 256;   // 4 waves; each wave owns 32 output cols
constexpr int BLK_ROWS = 64;    // 4 M-tiles of 16 rows
constexpr int SH_STRIDE = 132;  // u32 words per h row (128 + 4 pad)

typedef float v4f __attribute__((ext_vector_type(4)));
typedef float v2f __attribute__((ext_vector_type(2)));
typedef unsigned int v4u __attribute__((ext_vector_type(4)));
typedef short short8 __attribute__((ext_vector_type(8)));

union FU { float f; uint32_t u; };
union U8 { uint32_t u[4]; short8 v; };

__device__ __forceinline__ uint32_t pack_hi16(uint32_t odd, uint32_t even) {
  return (odd & 0xFFFF0000u) | (even >> 16);
}
__device__ __forceinline__ uint32_t pack_lo16(uint32_t odd, uint32_t even) {
  return (odd << 16) | (even & 0xFFFFu);
}

// 2-way bf16 split (truncation): a ~= bf16(hi)+bf16(mid), residual <= 2^-16 |a|
__device__ __forceinline__ void split2(float a, uint32_t& hi, uint32_t& mid) {
  FU c0; c0.f = a;
  uint32_t uh = c0.u & 0xFFFF0000u;
  FU fh; fh.u = uh;
  float r1 = a - fh.f;   // exact
  FU c1; c1.f = r1;
  hi = uh; mid = c1.u & 0xFFFF0000u;
}
// 3-way exact bf16 split
__device__ __forceinline__ void split3(float a, uint32_t& hi, uint32_t& mid, uint32_t& lo) {
  FU c0; c0.f = a;
  uint32_t uh = c0.u & 0xFFFF0000u;
  FU fh; fh.u = uh;
  float r1 = a - fh.f;
  FU c1; c1.f = r1;
  uint32_t um = c1.u & 0xFFFF0000u;
  FU fm; fm.u = um;
  float r2 = r1 - fm.f;
  FU c2; c2.f = r2;
  hi = uh; mid = um; lo = c2.u;
}

__device__ __forceinline__ v4f mfma16(short8 a, short8 b, v4f c) {
  return __builtin_amdgcn_mfma_f32_16x16x32_bf16(a, b, c, 0, 0, 0);
}

// VALU-pipe butterfly add (replaces ds_bpermute __shfl_xor)
template<int CTRL>
__device__ __forceinline__ float dpp_radd(float x) {
  FU a; a.f = x;
  FU b; b.u = (uint32_t)__builtin_amdgcn_update_dpp(0, (int)a.u, CTRL, 0xF, 0xF, true);
  return x + b.f;
}
// sum over the 16 lanes of each lane-group (o = lane&15); result in all 16.
// xor1=quad_perm[1,0,3,2], xor2=quad_perm[2,3,0,1], xor4==row_half_mirror
// (uniform within quads by then), xor8==row_mirror (uniform within 8).
__device__ __forceinline__ float red16(float x) {
  x = dpp_radd<0xB1>(x);
  x = dpp_radd<0x4E>(x);
  x = dpp_radd<0x141>(x);
  x = dpp_radd<0x140>(x);
  return x;
}

__global__ __launch_bounds__(NTHREADS, 2)
void fwdsim6(const float* __restrict__ proj,   // (B, 64)
             const float* __restrict__ idm,    // (B, T, 12)
             const float* __restrict__ merg,   // (B, T, 3)
             const float* __restrict__ W1,     // (73, 128)
             const float* __restrict__ b1,     // (128)
             const float* __restrict__ W2,     // (128, 128)
             const float* __restrict__ b2,     // (128)
             const float* __restrict__ W3,     // (128, 1)
             const float* __restrict__ b3,     // (1)
             const float* __restrict__ smean,  // (6)
             const float* __restrict__ svar,   // (6)
             float* __restrict__ out)          // (B, T)
{
  // h exchange: [row 64][132] packed bf16 hi|mid (col 0..127 live, 4 pad)
  __shared__ __align__(16) uint32_t sH[64 * SH_STRIDE];   // 33792 B
  // layer-3 partials: [buf][row 64][member 4]
  __shared__ __align__(16) float sAct[2][64][4];          // 2048 B
  // output staging (coalesced flush at end)
  __shared__ __align__(16) float sOut[64 * T];            // 12800 B
  // total 48640 B -> 2 blocks/CU (8 waves/CU = 2 waves/SIMD)

  const int tid  = threadIdx.x;
  const int wave = tid >> 6;    // 0..3: owns output cols wave*32 .. wave*32+31
  const int lane = tid & 63;
  const int gq   = lane >> 4;   // 0..3
  const int o    = lane & 15;   // 0..15
  const int row0 = blockIdx.x * BLK_ROWS;

  // ---- scalars (wave-uniform ones land in SGPRs) ----
  float mean[6], istd[6];
#pragma unroll
  for (int c = 0; c < 6; ++c) { mean[c] = smean[c]; istd[c] = 1.0f / sqrtf(svar[c]); }
  const float b3v = b3[0];
  float b1c[2], b2c[2], W3c[2];
#pragma unroll
  for (int ntl = 0; ntl < 2; ++ntl) {
    const int n = (wave * 2 + ntl) * 16 + o;
    b1c[ntl] = b1[n]; b2c[ntl] = b2[n]; W3c[ntl] = W3[n];
  }

  // ---- W1 env rows 64..72 -> persistent register B-frags (2-plane, K padded to 32) ----
  short8 ebh[2], ebm[2];
#pragma unroll
  for (int ntl = 0; ntl < 2; ++ntl) {
    const int n = (wave * 2 + ntl) * 16 + o;
    uint32_t hi[8], mi[8];
#pragma unroll
    for (int j = 0; j < 8; ++j) {
      const int k = gq * 8 + j;
      const float w = (k < 9) ? W1[(64 + k) * H + n] : 0.f;
      split2(w, hi[j], mi[j]);
    }
    U8 fh, fm;
#pragma unroll
    for (int d = 0; d < 4; ++d) {
      fh.u[d] = pack_hi16(hi[2*d+1], hi[2*d]);
      fm.u[d] = pack_hi16(mi[2*d+1], mi[2*d]);
    }
    ebh[ntl] = fh.v; ebm[ntl] = fm.v;
  }

  // ---- W1[0:64] 3-plane frags (prologue-only, registers) ----
  short8 w1h[4], w1m[4], w1l[4];   // [kt*2+ntl]
#pragma unroll
  for (int kt = 0; kt < 2; ++kt)
#pragma unroll
    for (int ntl = 0; ntl < 2; ++ntl) {
      const int k0 = kt * 32 + gq * 8;
      const int n  = (wave * 2 + ntl) * 16 + o;
      uint32_t hi[8], mi[8], lo[8];
#pragma unroll
      for (int j = 0; j < 8; ++j) split3(W1[(k0 + j) * H + n], hi[j], mi[j], lo[j]);
      U8 fh, fm, fl;
#pragma unroll
      for (int d = 0; d < 4; ++d) {
        fh.u[d] = pack_hi16(hi[2*d+1], hi[2*d]);
        fm.u[d] = pack_hi16(mi[2*d+1], mi[2*d]);
        fl.u[d] = pack_hi16(lo[2*d+1], lo[2*d]);
      }
      w1h[kt*2+ntl] = fh.v; w1m[kt*2+ntl] = fm.v; w1l[kt*2+ntl] = fl.v;
    }

  // ---- base1 = b1 + proj @ W1[0:64] via 6-term exact-split MFMA -> registers ----
  // base[mt*2+ntl][r] = base1 for row mt*16+4gq+r, col (wave*2+ntl)*16+o
  v4f base[8];
#pragma unroll
  for (int mt = 0; mt < 4; ++mt) {
    const int row = row0 + mt * 16 + o;
    short8 pah[2], pam[2], pal[2];
#pragma unroll
    for (int kt = 0; kt < 2; ++kt) {
      const float* pp = proj + (size_t)row * 64 + kt * 32 + gq * 8;
      v4f p0 = *(const v4f*)pp;
      v4f p1 = *(const v4f*)(pp + 4);
      uint32_t hi[8], mi[8], lo[8];
#pragma unroll
      for (int e = 0; e < 4; ++e) split3(p0[e], hi[e],   mi[e],   lo[e]);
#pragma unroll
      for (int e = 0; e < 4; ++e) split3(p1[e], hi[4+e], mi[4+e], lo[4+e]);
      U8 uh, um, ul;
#pragma unroll
      for (int d = 0; d < 4; ++d) {
        uh.u[d] = pack_hi16(hi[2*d+1], hi[2*d]);
        um.u[d] = pack_hi16(mi[2*d+1], mi[2*d]);
        ul.u[d] = pack_hi16(lo[2*d+1], lo[2*d]);
      }
      pah[kt] = uh.v; pam[kt] = um.v; pal[kt] = ul.v;
    }
#pragma unroll
    for (int ntl = 0; ntl < 2; ++ntl) {
      v4f acc = (v4f){b1c[ntl], b1c[ntl], b1c[ntl], b1c[ntl]};
#pragma unroll
      for (int kt = 0; kt < 2; ++kt) {
        short8 bh = w1h[kt*2+ntl], bm = w1m[kt*2+ntl], bl = w1l[kt*2+ntl];
        acc = mfma16(pah[kt], bl, acc);
        acc = mfma16(pal[kt], bh, acc);
        acc = mfma16(pam[kt], bm, acc);
        acc = mfma16(pah[kt], bm, acc);
        acc = mfma16(pam[kt], bh, acc);
        acc = mfma16(pah[kt], bh, acc);
      }
      base[mt*2+ntl] = acc;
    }
  }

  // ---- W2 -> persistent register B-frags, this wave's 2 col-tiles only ----
  short8 w2h[8], w2m[8];   // [kt*2+ntl], kt 0..3
#pragma unroll
  for (int kt = 0; kt < 4; ++kt)
#pragma unroll
    for (int ntl = 0; ntl < 2; ++ntl) {
      const int k0 = kt * 32 + gq * 8;
      const int n  = (wave * 2 + ntl) * 16 + o;
      uint32_t hi[8], mi[8];
#pragma unroll
      for (int j = 0; j < 8; ++j) split2(W2[(k0 + j) * H + n], hi[j], mi[j]);
      U8 fh, fm;
#pragma unroll
      for (int d = 0; d < 4; ++d) {
        fh.u[d] = pack_hi16(hi[2*d+1], hi[2*d]);
        fm.u[d] = pack_hi16(mi[2*d+1], mi[2*d]);
      }
      w2h[kt*2+ntl] = fh.v;
      w2m[kt*2+ntl] = fm.v;
    }

  // ---- recurrent state: lane handles rows mt*16+o, replicated over gq (and waves) ----
  float ego_v[4], ego_x[4], act[4] = {0.f, 0.f, 0.f, 0.f};
  const float* idmp[4];
  const float* mrgp[4];
  v4f sa[4]; v2f fb[4]; float exr[4], m0[4], m1[4], m2[4];
#pragma unroll
  for (int mt = 0; mt < 4; ++mt) {
    idmp[mt] = idm  + (size_t)(row0 + mt*16 + o) * (T*12);
    mrgp[mt] = merg + (size_t)(row0 + mt*16 + o) * (T*3);
    sa[mt] = *(const v4f*)idmp[mt];
    fb[mt] = *(const v2f*)(idmp[mt] + 4);
    exr[mt] = idmp[mt][11];
    m0[mt] = mrgp[mt][0]; m1[mt] = mrgp[mt][1]; m2[mt] = mrgp[mt][2];
  }

  int buf = 0;

#pragma unroll 1
  for (int t = 0; t < T; ++t) {
    // ======== phase A: state + env + layer 1 -> sH (own 32 cols) ========
#pragma unroll
    for (int mt = 0; mt < 4; ++mt) {
      const float s0 = sa[mt][0], fv = sa[mt][1], mv = sa[mt][2], s3 = sa[mt][3];
      const float fgx = fb[mt][0], mgx = fb[mt][1];
      const float ex = exr[mt];
      if (t == 0) { ego_v[mt] = s0; ego_x[mt] = s3; }
      else {
        ego_v[mt] += act[mt] * 0.1f;
        ego_x[mt] += ego_v[mt] * 0.1f + act[mt] * 0.005f;
      }
      float xk[9];
      xk[0] = (ego_v[mt]                                      - mean[0]) * istd[0];
      xk[1] = (fv                                             - mean[1]) * istd[1];
      xk[2] = (ego_v[mt] - fv                                 - mean[2]) * istd[2];
      xk[3] = (fgx - ego_x[mt]                                - mean[3]) * istd[3];
      xk[4] = ((ego_v[mt] - mv) * ex                          - mean[4]) * istd[4];
      xk[5] = ((mgx - ego_x[mt]) * ex + (1.0f - ex) * 100.0f  - mean[5]) * istd[5];
      xk[6] = m0[mt]; xk[7] = m1[mt]; xk[8] = m2[mt];

      // env A-frag: A[m=o][k=8gq+j]; dims 9..31 zero
      uint32_t hi[8], mi[8];
#pragma unroll
      for (int j = 0; j < 8; ++j) {
        float v = (gq == 0) ? xk[j] : ((gq == 1 && j == 0) ? xk[8] : 0.f);
        split2(v, hi[j], mi[j]);
      }
      U8 uh, um;
#pragma unroll
      for (int d = 0; d < 4; ++d) {
        uh.u[d] = pack_hi16(hi[2*d+1], hi[2*d]);
        um.u[d] = pack_hi16(mi[2*d+1], mi[2*d]);
      }
      short8 eh = uh.v, em = um.v;

#pragma unroll
      for (int ntl = 0; ntl < 2; ++ntl) {
        v4f a1 = base[mt*2+ntl];
        a1 = mfma16(eh, ebm[ntl], a1);
        a1 = mfma16(em, ebh[ntl], a1);
        a1 = mfma16(eh, ebh[ntl], a1);
#pragma unroll
        for (int r = 0; r < 4; ++r) {
          const float hv = fmaxf(a1[r], 0.f);
          uint32_t h_, m_; split2(hv, h_, m_);
          sH[(mt*16 + 4*gq + r) * SH_STRIDE + (wave*2+ntl)*16 + o] = h_ | (m_ >> 16);
        }
      }
    }

    __syncthreads();   // B1: full h visible

    // issue next-step input loads; they fly under layer 2, drained at B2
    v4f nsa[4]; v2f nfb[4]; float nex[4], nm0[4], nm1[4], nm2[4];
    {
      const int tn = (t + 1 < T) ? t + 1 : t;
#pragma unroll
      for (int mt = 0; mt < 4; ++mt) {
        const float* ip = idmp[mt] + tn * 12;
        nsa[mt] = *(const v4f*)ip;  nfb[mt] = *(const v2f*)(ip + 4);  nex[mt] = ip[11];
        const float* mp = mrgp[mt] + tn * 3;
        nm0[mt] = mp[0]; nm1[mt] = mp[1]; nm2[mt] = mp[2];
      }
    }

    // ======== phase B: layer 2 (full K from sH) + layer-3 partial ========
#pragma unroll
    for (int mt = 0; mt < 4; ++mt) {
      v4f acc2[2];
#pragma unroll
      for (int ntl = 0; ntl < 2; ++ntl)
        acc2[ntl] = (v4f){b2c[ntl], b2c[ntl], b2c[ntl], b2c[ntl]};

#pragma unroll
      for (int kt = 0; kt < 4; ++kt) {
        const uint32_t* src = &sH[(mt*16 + o) * SH_STRIDE + kt*32 + gq*8];
        v4u q0 = *(const v4u*)src;
        v4u q1 = *(const v4u*)(src + 4);
        uint32_t u[8] = {q0[0], q0[1], q0[2], q0[3], q1[0], q1[1], q1[2], q1[3]};
        U8 uh, um;
#pragma unroll
        for (int d = 0; d < 4; ++d) {
          uh.u[d] = pack_hi16(u[2*d+1], u[2*d]);   // hi plane
          um.u[d] = pack_lo16(u[2*d+1], u[2*d]);   // mid plane
        }
        short8 ah = uh.v, am = um.v;
#pragma unroll
        for (int ntl = 0; ntl < 2; ++ntl) {
          acc2[ntl] = mfma16(ah, w2m[kt*2+ntl], acc2[ntl]);
          acc2[ntl] = mfma16(am, w2h[kt*2+ntl], acc2[ntl]);
          acc2[ntl] = mfma16(ah, w2h[kt*2+ntl], acc2[ntl]);
        }
      }

      // layer-3 partial over this wave's 32 cols
      v4f part = (v4f){0.f, 0.f, 0.f, 0.f};
#pragma unroll
      for (int ntl = 0; ntl < 2; ++ntl)
#pragma unroll
        for (int r = 0; r < 4; ++r)
          part[r] += fmaxf(acc2[ntl][r], 0.f) * W3c[ntl];
#pragma unroll
      for (int r = 0; r < 4; ++r) part[r] = red16(part[r]);   // VALU butterfly

      // spread store: lane (gq, o<4) writes row mt*16+4gq+o, one ds_write
      const float pv = (o & 2) ? ((o & 1) ? part[3] : part[2])
                               : ((o & 1) ? part[1] : part[0]);
      if (o < 4) sAct[buf][mt*16 + 4*gq + o][wave] = pv;
    }

    __syncthreads();   // B2: partials visible; sH reads done (WAR for t+1)

    // act = sum of 4 member partials + b3
#pragma unroll
    for (int mt = 0; mt < 4; ++mt) {
      v4f pa = *(const v4f*)&sAct[buf][mt*16 + o][0];
      act[mt] = ((pa[0] + pa[1]) + (pa[2] + pa[3])) + b3v;
    }
    if (wave == 0 && gq == 0) {
#pragma unroll
      for (int mt = 0; mt < 4; ++mt)
        sOut[(mt*16 + o) * T + t] = act[mt];
    }

    // roll prefetched inputs
#pragma unroll
    for (int mt = 0; mt < 4; ++mt) {
      sa[mt] = nsa[mt]; fb[mt] = nfb[mt]; exr[mt] = nex[mt];
      m0[mt] = nm0[mt]; m1[mt] = nm1[mt]; m2[mt] = nm2[mt];
    }
    buf ^= 1;
  }

  // ---- coalesced output flush ----
  __syncthreads();
  float* obase = out + (size_t)row0 * T;
  for (int idx = tid; idx < BLK_ROWS * T; idx += NTHREADS)
    obase[idx] = sOut[idx];
}

}  // namespace

extern "C" void kernel_launch(void* const* d_in, const int* in_sizes, int n_in,
                              void* d_out, int out_size, void* d_ws, size_t ws_size,
                              hipStream_t stream) {
  const float* proj  = (const float*)d_in[0];
  const float* idm   = (const float*)d_in[1];
  const float* merg  = (const float*)d_in[2];
  const float* W1    = (const float*)d_in[3];
  const float* b1    = (const float*)d_in[4];
  const float* W2    = (const float*)d_in[5];
  const float* b2    = (const float*)d_in[6];
  const float* W3    = (const float*)d_in[7];
  const float* b3    = (const float*)d_in[8];
  const float* smean = (const float*)d_in[9];
  const float* svar  = (const float*)d_in[10];
  // d_in[11] = rollout_len (fixed 50)

  dim3 grid(NB / BLK_ROWS);   // 512 blocks -> 2 per CU, single pass
  dim3 block(NTHREADS);       // 256 threads = 4 waves x 64 rows
  hipLaunchKernelGGL(fwdsim6, grid, block, 0, stream,
                     proj, idm, merg, W1, b1, W2, b2, W3, b3, smean, svar,
                     (float*)d_out);
}